// Round 8
// baseline (61.995 us; speedup 1.0000x reference)
//
#include <hip/hip_runtime.h>
#include <math.h>

#define H 1024
#define S 2048
#define B 32

// Kernel 1: v[b,h] = sum_k hidden[b,k] * W[k,h]
// grid 256 = (bg: 16 groups of 2 b) x (hc: 16 chunks of 64 cols)
// 512 threads = (kg = t>>4: 32 k-groups) x (hq = t&15: 16 float4 columns)
__global__ void __launch_bounds__(512)
proj_hidden_kernel(const float* __restrict__ hidden,
                   const float* __restrict__ W,
                   float* __restrict__ v) {
    __shared__ float hs[2][H];          // 8 KB
    __shared__ float part[32][2][64];   // 16 KB
    const int hc = blockIdx.x & 15;
    const int bg = blockIdx.x >> 4;
    const int hq = threadIdx.x & 15;
    const int kg = threadIdx.x >> 4;

    for (int i = threadIdx.x; i < 2 * H; i += 512)
        hs[i >> 10][i & 1023] = hidden[(bg * 2 + (i >> 10)) * H + (i & 1023)];
    __syncthreads();

    const int h = hc * 64 + hq * 4;
    float4 a0 = {0.f, 0.f, 0.f, 0.f};
    float4 a1 = {0.f, 0.f, 0.f, 0.f};
#pragma unroll 4
    for (int kk = 0; kk < 32; ++kk) {
        const int k = kg + 32 * kk;
        const float h0 = hs[0][k];
        const float h1 = hs[1][k];
        const float4 w = *reinterpret_cast<const float4*>(W + (size_t)k * H + h);
        a0.x = fmaf(h0, w.x, a0.x); a0.y = fmaf(h0, w.y, a0.y);
        a0.z = fmaf(h0, w.z, a0.z); a0.w = fmaf(h0, w.w, a0.w);
        a1.x = fmaf(h1, w.x, a1.x); a1.y = fmaf(h1, w.y, a1.y);
        a1.z = fmaf(h1, w.z, a1.z); a1.w = fmaf(h1, w.w, a1.w);
    }
    *reinterpret_cast<float4*>(&part[kg][0][hq * 4]) = a0;
    *reinterpret_cast<float4*>(&part[kg][1][hq * 4]) = a1;
    __syncthreads();

    if (threadIdx.x < 128) {
        const int bb = threadIdx.x >> 6;
        const int c  = threadIdx.x & 63;
        float sum = 0.f;
#pragma unroll 8
        for (int g = 0; g < 32; ++g) sum += part[g][bb][c];
        v[(bg * 2 + bb) * H + hc * 64 + c] = sum;
    }
}

// Kernel 2: scores[b,s] = dot(enc[s,b,:], v[b,:])
// grid = 512 blocks x 512 threads (8 waves). Block owns 128 consecutive
// (s,b) rows = 512 KB CONTIGUOUS enc. Each wave owns 16 whole rows; per row
// the wave issues 4 fully-contiguous 1 KB load instructions (lane-major).
// v (128 KB, all 32 b) staged in dynamic LDS once per block; per-row
// fragments via conflict-free ds_read_b128. 4 rows reduced concurrently.
__global__ void __launch_bounds__(512)
scores_kernel(const float* __restrict__ enc,
              const float* __restrict__ v,
              float* __restrict__ scores) {
    extern __shared__ float vlds[];   // 32 * H floats = 128 KB
    const int wave = threadIdx.x >> 6;
    const int lane = threadIdx.x & 63;

    {
        const float4* v4 = reinterpret_cast<const float4*>(v);
        float4* s4 = reinterpret_cast<float4*>(vlds);
        for (int i = threadIdx.x; i < (32 * H) / 4; i += 512)
            s4[i] = v4[i];
    }
    __syncthreads();

    const size_t g0 = (size_t)blockIdx.x * 128 + (size_t)wave * 16;  // first row
    const float4* enc4 = reinterpret_cast<const float4*>(enc) + g0 * (H / 4);

    for (int i = 0; i < 16; i += 4) {
        float a0 = 0.f, a1 = 0.f, a2 = 0.f, a3 = 0.f;
#define ROW(acc, r)                                                          \
        {                                                                    \
            const float4* ep = enc4 + (size_t)(i + (r)) * (H / 4);           \
            const int b = (int)((g0 + i + (r)) & 31);                        \
            const float4* vp = reinterpret_cast<const float4*>(vlds + b * H);\
            _Pragma("unroll")                                                \
            for (int q = 0; q < 4; ++q) {                                    \
                const float4 e = ep[lane + 64 * q];                          \
                const float4 w = vp[lane + 64 * q];                          \
                acc = fmaf(e.x, w.x, fmaf(e.y, w.y,                          \
                      fmaf(e.z, w.z, fmaf(e.w, w.w, acc))));                 \
            }                                                                \
        }
        ROW(a0, 0) ROW(a1, 1) ROW(a2, 2) ROW(a3, 3)
#undef ROW
        // four interleaved 64-lane butterflies
#pragma unroll
        for (int off = 32; off > 0; off >>= 1) {
            a0 += __shfl_down(a0, off, 64);
            a1 += __shfl_down(a1, off, 64);
            a2 += __shfl_down(a2, off, 64);
            a3 += __shfl_down(a3, off, 64);
        }
        if (lane == 0) {
            const size_t g = g0 + i;
            scores[((g + 0) & 31) * S + ((g + 0) >> 5)] = a0;
            scores[((g + 1) & 31) * S + ((g + 1) >> 5)] = a1;
            scores[((g + 2) & 31) * S + ((g + 2) >> 5)] = a2;
            scores[((g + 3) & 31) * S + ((g + 3) >> 5)] = a3;
        }
    }
}

// Kernel 3: out[b, :] = softmax(scores[b, :]) ; one block per b.
__global__ void __launch_bounds__(256)
softmax_kernel(const float* __restrict__ scores,
               float* __restrict__ out) {
    const int b    = blockIdx.x;
    const int tid  = threadIdx.x;
    const int wave = tid >> 6;
    const int lane = tid & 63;

    __shared__ float wmax[4];
    __shared__ float wsum[4];

    float x[8];
    float m = -INFINITY;
#pragma unroll
    for (int i = 0; i < 8; ++i) {
        x[i] = scores[(size_t)b * S + tid + i * 256];
        m = fmaxf(m, x[i]);
    }
#pragma unroll
    for (int off = 32; off > 0; off >>= 1)
        m = fmaxf(m, __shfl_down(m, off, 64));
    if (lane == 0) wmax[wave] = m;
    __syncthreads();
    m = fmaxf(fmaxf(wmax[0], wmax[1]), fmaxf(wmax[2], wmax[3]));

    float sum = 0.f;
#pragma unroll
    for (int i = 0; i < 8; ++i) {
        x[i] = __expf(x[i] - m);
        sum += x[i];
    }
#pragma unroll
    for (int off = 32; off > 0; off >>= 1)
        sum += __shfl_down(sum, off, 64);
    if (lane == 0) wsum[wave] = sum;
    __syncthreads();
    sum = (wsum[0] + wsum[1]) + (wsum[2] + wsum[3]);

    const float inv = 1.0f / sum;
#pragma unroll
    for (int i = 0; i < 8; ++i) {
        out[(size_t)b * S + tid + i * 256] = x[i] * inv;
    }
}

extern "C" void kernel_launch(void* const* d_in, const int* in_sizes, int n_in,
                              void* d_out, int out_size, void* d_ws, size_t ws_size,
                              hipStream_t stream) {
    const float* hidden = (const float*)d_in[0];   // (1, B, H)
    const float* enc    = (const float*)d_in[1];   // (S, B, H)
    const float* W      = (const float*)d_in[2];   // (H, H)
    // d_in[3] = bias: per-b constant shift in scores -> cancelled by softmax.

    float* v      = (float*)d_ws;        // B*H floats
    float* scores = v + (size_t)B * H;   // B*S floats
    float* out    = (float*)d_out;       // B*S floats

    proj_hidden_kernel<<<256, 512, 0, stream>>>(hidden, W, v);
    scores_kernel<<<512, 512, 32 * H * sizeof(float), stream>>>(enc, v, scores);
    softmax_kernel<<<B, 256, 0, stream>>>(scores, out);
}